// Round 8
// baseline (772.198 us; speedup 1.0000x reference)
//
#include <hip/hip_runtime.h>
#include <hip/hip_bf16.h>

// Problem constants
#define NF 32          // n_features
#define NCH 64         // n_channels
#define TRAW 16384     // raw samples
#define TPAD 16448     // TRAW + 64 (left reflect pad)
#define TP 4112        // TPAD / 4
#define TE 4104        // TP - 8  (after encoder MA, kernel size 9)
#define TD 4096        // TE - 8  (after decoder MA) == TRAW/4

// Workspace layout (floats)
#define OFF_SPAD   0u                     // [32][16448]
#define OFF_AMEAN  526336u                // [32][4112]
#define OFF_ACOV   657920u                // [4112][1024] t-major
#define OFF_XMEAN  4868608u               // [32][4104]
#define OFF_XCOV   4999936u               // [4104][1024] t-major
#define OFF_FET_E  9202432u               // [8][32][32] transposed encoder MA filter
#define OFF_FET_D  9210624u               // [8][32][32] transposed decoder MA filter
// reuse: AMEANT aliases AMEAN (consumed), ACOVT aliases ACOV (consumed)
#define OFF_AMEANT OFF_AMEAN              // [32][4096]
#define OFF_ACOVT  OFF_ACOV               // [4096][1024]

// ---------------------------------------------------------------------------
// 0) feT[k*1024 + C*32 + c] = maw[(c*NF + C)*8 + k]   (32 KB, one-shot)
__global__ void feprep_kernel(const float* __restrict__ maw, float* __restrict__ feT) {
    int idx = blockIdx.x * 256 + threadIdx.x;   // 0..8191
    int k = idx >> 10, r = idx & 1023;
    int C = r >> 5, c = r & 31;
    feT[idx] = maw[(c * NF + C) * 8 + k];
}

// ---------------------------------------------------------------------------
// 1) s_pad[f,t] = sum_c W_enc[f,c] * y_pad[c,t],  y_pad[c,t] = y[c, |t-64|]
__global__ void senc_kernel(const float* __restrict__ y,
                            const float* __restrict__ Wenc,
                            float* __restrict__ spad) {
    int t = blockIdx.x * 256 + threadIdx.x;
    int f = blockIdx.y;
    if (t >= TPAD) return;
    int tt = (t >= 64) ? (t - 64) : (64 - t);   // reflect pad
    float acc = 0.f;
#pragma unroll
    for (int c = 0; c < NCH; ++c)
        acc = fmaf(Wenc[f * NCH + c], y[c * TRAW + tt], acc);
    spad[f * TPAD + t] = acc;
}

// ---------------------------------------------------------------------------
// 2) per-t4 stats: a_mean[f,t4], a_cov[t4][c][s]  (8 t4 per block)
__global__ __launch_bounds__(256) void stats_kernel(const float* __restrict__ spad,
                                                    float* __restrict__ amean,
                                                    float* __restrict__ acov) {
    __shared__ float sab[32][33];   // padded (bank conflicts)
    __shared__ float mu[32][9];
    int tid = threadIdx.x;
    int t0 = blockIdx.x * 8;        // 514 blocks * 8 = 4112
#pragma unroll
    for (int i = 0; i < 4; ++i) {
        int idx = tid + 256 * i;    // 0..1023
        int f = idx >> 5, j = idx & 31;
        sab[f][j] = fabsf(spad[f * TPAD + t0 * 4 + j]);
    }
    __syncthreads();
    {
        int f = tid >> 3, tt = tid & 7;
        float m = 0.25f * (sab[f][tt * 4] + sab[f][tt * 4 + 1] +
                           sab[f][tt * 4 + 2] + sab[f][tt * 4 + 3]);
        mu[f][tt] = m;
        amean[f * TP + t0 + tt] = m;
    }
    __syncthreads();
    const float inv3 = 1.f / 3.f;
#pragma unroll
    for (int e = 0; e < 32; ++e) {
        int flat = e * 256 + tid;   // 0..8191
        int tt = flat >> 10, r = flat & 1023;
        int c = r >> 5, s = r & 31;
        float mc = mu[c][tt], ms = mu[s][tt];
        float acc = 0.f;
#pragma unroll
        for (int d = 0; d < 4; ++d)
            acc += (sab[c][tt * 4 + d] - mc) * (sab[s][tt * 4 + d] - ms);
        acov[(size_t)(t0 + tt) * 1024 + r] = acc * inv3;
    }
}

// ---------------------------------------------------------------------------
// 3/5) mean MA: out[c,t] = b[c] + in[c,t+8] + sum_{k<8,C} w[c,C,k]*in[C,t+k]
__global__ void mamean_kernel(const float* __restrict__ in, int instride,
                              const float* __restrict__ w,
                              const float* __restrict__ b,
                              float* __restrict__ outp, int Tout) {
    int t = blockIdx.x * 256 + threadIdx.x;
    int c = blockIdx.y;
    if (t >= Tout) return;
    float acc = b[c] + in[c * instride + t + 8];
    for (int C = 0; C < NF; ++C) {
#pragma unroll
        for (int k = 0; k < 8; ++k)
            acc = fmaf(w[(c * NF + C) * 8 + k], in[C * instride + t + k], acc);
    }
    outp[c * Tout + t] = acc;
}

// ---------------------------------------------------------------------------
// 4/6) cov MA v6: out_t[c][s] = scale*( A_{t+8}[c][s] +
//        sum_{k<8} sum_C F[c][C][k] * h_k[C][s] ), h_k[C][s]=sum_S A_{t+k}[C][S]*F[s][S][k]
//  One 64-thread block per t. ALL broadcast operands (A chunks, fe rows) have
//  wave-uniform addresses (t = blockIdx.x only) -> compiler selects s_load
//  (scalar pipe / K$), bypassing the LDS pipe that bound v5. Per-lane data:
//  fsk[32] (VGPR, coalesced) + acc[32]. Halves duplicate compute, split store.
__global__ __launch_bounds__(64, 4) void macov_kernel(const float* __restrict__ Ain,
                                                      const float* __restrict__ feT,
                                                      const float* __restrict__ scale_ptr,
                                                      float* __restrict__ Aout) {
    int t = blockIdx.x;
    int l = threadIdx.x;
    int s = l & 31;
    int half = l >> 5;
    float acc[32];
#pragma unroll
    for (int c = 0; c < 32; ++c) acc[c] = 0.f;

#pragma unroll 1
    for (int k = 0; k < 8; ++k) {
        const float* fk = feT + (k << 10);
        float fsk[32];               // F[s][S][k] = fk[S*32+s], per-lane, coalesced
#pragma unroll
        for (int S = 0; S < 32; ++S) fsk[S] = fk[S * 32 + s];
        const float* Arow = Ain + (size_t)(t + k) * 1024;    // uniform
#pragma unroll 1
        for (int C = 0; C < 32; ++C) {
            const float4* A4 = (const float4*)(Arow + C * 32);   // uniform -> s_load
            float4 a0 = A4[0], a1 = A4[1], a2 = A4[2], a3 = A4[3];
            float4 a4 = A4[4], a5 = A4[5], a6 = A4[6], a7 = A4[7];
            float h0 = 0.f, h1 = 0.f, h2 = 0.f, h3 = 0.f;
            h0 = fmaf(a0.x, fsk[0],  h0); h0 = fmaf(a0.y, fsk[1],  h0);
            h1 = fmaf(a0.z, fsk[2],  h1); h1 = fmaf(a0.w, fsk[3],  h1);
            h0 = fmaf(a1.x, fsk[4],  h0); h0 = fmaf(a1.y, fsk[5],  h0);
            h1 = fmaf(a1.z, fsk[6],  h1); h1 = fmaf(a1.w, fsk[7],  h1);
            h2 = fmaf(a2.x, fsk[8],  h2); h2 = fmaf(a2.y, fsk[9],  h2);
            h3 = fmaf(a2.z, fsk[10], h3); h3 = fmaf(a2.w, fsk[11], h3);
            h2 = fmaf(a3.x, fsk[12], h2); h2 = fmaf(a3.y, fsk[13], h2);
            h3 = fmaf(a3.z, fsk[14], h3); h3 = fmaf(a3.w, fsk[15], h3);
            h0 = fmaf(a4.x, fsk[16], h0); h0 = fmaf(a4.y, fsk[17], h0);
            h1 = fmaf(a4.z, fsk[18], h1); h1 = fmaf(a4.w, fsk[19], h1);
            h0 = fmaf(a5.x, fsk[20], h0); h0 = fmaf(a5.y, fsk[21], h0);
            h1 = fmaf(a5.z, fsk[22], h1); h1 = fmaf(a5.w, fsk[23], h1);
            h2 = fmaf(a6.x, fsk[24], h2); h2 = fmaf(a6.y, fsk[25], h2);
            h3 = fmaf(a6.z, fsk[26], h3); h3 = fmaf(a6.w, fsk[27], h3);
            h2 = fmaf(a7.x, fsk[28], h2); h2 = fmaf(a7.y, fsk[29], h2);
            h3 = fmaf(a7.z, fsk[30], h3); h3 = fmaf(a7.w, fsk[31], h3);
            float h = (h0 + h1) + (h2 + h3);
            const float4* F4 = (const float4*)(fk + C * 32);     // uniform -> s_load
#pragma unroll
            for (int j = 0; j < 8; ++j) {
                float4 f = F4[j];
                acc[4 * j + 0] = fmaf(f.x, h, acc[4 * j + 0]);
                acc[4 * j + 1] = fmaf(f.y, h, acc[4 * j + 1]);
                acc[4 * j + 2] = fmaf(f.z, h, acc[4 * j + 2]);
                acc[4 * j + 3] = fmaf(f.w, h, acc[4 * j + 3]);
            }
        }
    }
    // identity (k=8) + scale + store; half h stores rows c = h*16..h*16+15.
    float sc = scale_ptr ? *scale_ptr : 1.f;
    const float* A8 = Ain + (size_t)(t + 8) * 1024;
    float* Orow = Aout + (size_t)t * 1024;
#pragma unroll
    for (int e = 0; e < 16; ++e) {
        float v = half ? acc[e + 16] : acc[e];   // static reg indices (no scratch)
        int c = half * 16 + e;
        Orow[c * 32 + s] = (v + A8[c * 32 + s]) * sc;
    }
}

// ---------------------------------------------------------------------------
// 7) y_mean rows 0..63: out[o,t] = sum_f Wdec[o,f]*a_mean_t[f,t/4]*sgn(spad[f,t+64])
__global__ void ymean_kernel(const float* __restrict__ spad,
                             const float* __restrict__ ameant,
                             const float* __restrict__ Wdec,
                             float* __restrict__ out) {
    int t = blockIdx.x * 256 + threadIdx.x;   // < 16384
    int o = blockIdx.y;
    int t4 = t >> 2;
    float acc = 0.f;
#pragma unroll
    for (int f = 0; f < NF; ++f) {
        float sp = spad[f * TPAD + 64 + t];
        float sgn = (sp > 0.f) ? 1.f : (sp < 0.f ? -1.f : 0.f);
        acc = fmaf(Wdec[o * NF + f], ameant[f * TD + t4] * sgn, acc);
    }
    out[o * TRAW + t] = acc;
}

// ---------------------------------------------------------------------------
// 8) y_cov v2 rows 64..4159. Block owns 4 consecutive t4; writes full 64B lines.
//    LDS: W2 (8KB, row-major for b128 bcast) + B4 (32.9KB padded) = 40.9 KB.
#define B4S 2056   // padded per-t4 stride (floats)
__global__ __launch_bounds__(256) void ycov_kernel(const float* __restrict__ Acovt,
                                                   const float* __restrict__ Wdec,
                                                   float* __restrict__ out) {
    __shared__ __align__(16) float W2[64 * 32];   // W2[o*32+i] = Wdec[o][i]
    __shared__ __align__(16) float B4[4 * B4S];   // B4[t4l*B4S + o*32 + I]
    int tid = threadIdx.x;
    int T0 = blockIdx.x * 4;        // gridDim.x == 1024

#pragma unroll
    for (int i = 0; i < 8; ++i) {
        int idx = tid + 256 * i;    // 0..2047, coalesced
        W2[idx] = Wdec[idx];
    }
    __syncthreads();

    // B-stage: wave = one t4. B[t4][o][I] = sum_i Wdec[o][i] * A[t4][i][I]
    {
        int t4l = tid >> 6, I = tid & 31, half = (tid >> 5) & 1;
        const float* Arow = Acovt + (size_t)(T0 + t4l) * 1024;
        float areg[32];
#pragma unroll
        for (int i = 0; i < 32; ++i) areg[i] = Arow[i * 32 + I];  // coalesced
        float* Bb = B4 + t4l * B4S + I;
#pragma unroll 4
        for (int oj = 0; oj < 32; ++oj) {
            int o = half * 32 + oj;
            const float4* Wr = (const float4*)(W2 + o * 32);      // b128 bcast
            float a0 = 0.f, a1 = 0.f, a2 = 0.f, a3 = 0.f;
#pragma unroll
            for (int j = 0; j < 8; j += 4) {
                float4 w0 = Wr[j], w1 = Wr[j + 1], w2 = Wr[j + 2], w3 = Wr[j + 3];
                a0 = fmaf(w0.x, areg[4 * j + 0], a0);  a0 = fmaf(w0.y, areg[4 * j + 1], a0);
                a1 = fmaf(w0.z, areg[4 * j + 2], a1);  a1 = fmaf(w0.w, areg[4 * j + 3], a1);
                a0 = fmaf(w1.x, areg[4 * j + 4], a0);  a0 = fmaf(w1.y, areg[4 * j + 5], a0);
                a1 = fmaf(w1.z, areg[4 * j + 6], a1);  a1 = fmaf(w1.w, areg[4 * j + 7], a1);
                a2 = fmaf(w2.x, areg[4 * j + 8], a2);  a2 = fmaf(w2.y, areg[4 * j + 9], a2);
                a3 = fmaf(w2.z, areg[4 * j + 10], a3); a3 = fmaf(w2.w, areg[4 * j + 11], a3);
                a2 = fmaf(w3.x, areg[4 * j + 12], a2); a2 = fmaf(w3.y, areg[4 * j + 13], a2);
                a3 = fmaf(w3.z, areg[4 * j + 14], a3); a3 = fmaf(w3.w, areg[4 * j + 15], a3);
            }
            Bb[o * 32] = (a0 + a1) + (a2 + a3);
        }
    }
    __syncthreads();

    // M-stage: lane owns (O = tid>>2, t4l = tid&3); loops o. Full-line stores.
    {
        int O = tid >> 2, t4l = tid & 3;
        float4 wv[8];
#pragma unroll
        for (int j = 0; j < 8; ++j) wv[j] = ((const float4*)(Wdec + O * 32))[j];
        float4* out4 = (float4*)out;
        const float* Bbase = B4 + t4l * B4S;
#pragma unroll 2
        for (int o = 0; o < 64; ++o) {
            const float4* Br = (const float4*)(Bbase + o * 32);
            float a0 = 0.f, a1 = 0.f, a2 = 0.f, a3 = 0.f;
#pragma unroll
            for (int j = 0; j < 8; j += 4) {
                float4 b0 = Br[j], b1 = Br[j + 1], b2 = Br[j + 2], b3 = Br[j + 3];
                a0 = fmaf(b0.x, wv[j].x, a0);      a0 = fmaf(b0.y, wv[j].y, a0);
                a1 = fmaf(b0.z, wv[j].z, a1);      a1 = fmaf(b0.w, wv[j].w, a1);
                a0 = fmaf(b1.x, wv[j + 1].x, a0);  a0 = fmaf(b1.y, wv[j + 1].y, a0);
                a1 = fmaf(b1.z, wv[j + 1].z, a1);  a1 = fmaf(b1.w, wv[j + 1].w, a1);
                a2 = fmaf(b2.x, wv[j + 2].x, a2);  a2 = fmaf(b2.y, wv[j + 2].y, a2);
                a3 = fmaf(b2.z, wv[j + 2].z, a3);  a3 = fmaf(b2.w, wv[j + 2].w, a3);
                a2 = fmaf(b3.x, wv[j + 3].x, a2);  a2 = fmaf(b3.y, wv[j + 3].y, a2);
                a3 = fmaf(b3.z, wv[j + 3].z, a3);  a3 = fmaf(b3.w, wv[j + 3].w, a3);
            }
            float acc = (a0 + a1) + (a2 + a3);
            size_t r = 64 + o * 64 + O;       // output row
            out4[r * (TRAW / 4) + T0 + t4l] = make_float4(acc, acc, acc, acc);
        }
    }
}

// ---------------------------------------------------------------------------
extern "C" void kernel_launch(void* const* d_in, const int* in_sizes, int n_in,
                              void* d_out, int out_size, void* d_ws, size_t ws_size,
                              hipStream_t stream) {
    const float* y      = (const float*)d_in[0];
    const float* Wenc   = (const float*)d_in[1];
    const float* Wdec   = (const float*)d_in[2];
    const float* mawE   = (const float*)d_in[3];
    const float* mabE   = (const float*)d_in[4];
    const float* mawD   = (const float*)d_in[5];
    const float* mabD   = (const float*)d_in[6];
    const float* covsc  = (const float*)d_in[7];
    float* out = (float*)d_out;
    float* ws  = (float*)d_ws;

    float* spad   = ws + OFF_SPAD;
    float* amean  = ws + OFF_AMEAN;
    float* acov   = ws + OFF_ACOV;
    float* xmean  = ws + OFF_XMEAN;
    float* xcov   = ws + OFF_XCOV;
    float* ameant = ws + OFF_AMEANT;
    float* acovt  = ws + OFF_ACOVT;
    float* fetE   = ws + OFF_FET_E;
    float* fetD   = ws + OFF_FET_D;

    // 0) transpose MA filters (32 KB each)
    feprep_kernel<<<dim3(32), 256, 0, stream>>>(mawE, fetE);
    feprep_kernel<<<dim3(32), 256, 0, stream>>>(mawD, fetD);
    // 1) spatial encode + pad
    senc_kernel<<<dim3((TPAD + 255) / 256, NF), 256, 0, stream>>>(y, Wenc, spad);
    // 2) downsample stats
    stats_kernel<<<dim3(TP / 8), 256, 0, stream>>>(spad, amean, acov);
    // 3) encoder mean MA
    mamean_kernel<<<dim3((TE + 255) / 256, NF), 256, 0, stream>>>(amean, TP, mawE, mabE, xmean, TE);
    // 4) encoder cov MA (scaled by cov_scaler) — one t per 64-thread block
    macov_kernel<<<dim3(TE), 64, 0, stream>>>(acov, fetE, covsc, xcov);
    // 5) decoder mean MA
    mamean_kernel<<<dim3((TD + 255) / 256, NF), 256, 0, stream>>>(xmean, TE, mawD, mabD, ameant, TD);
    // 6) decoder cov MA
    macov_kernel<<<dim3(TD), 64, 0, stream>>>(xcov, fetD, nullptr, acovt);
    // 7) y_mean
    ymean_kernel<<<dim3(TRAW / 256, NCH), 256, 0, stream>>>(spad, ameant, Wdec, out);
    // 8) y_cov — 4 t4 per block
    ycov_kernel<<<dim3(TD / 4), 256, 0, stream>>>(acovt, Wdec, out);
}

// Round 9
// 502.177 us; speedup vs baseline: 1.5377x; 1.5377x over previous
//
#include <hip/hip_runtime.h>
#include <hip/hip_bf16.h>

// Problem constants
#define NF 32          // n_features
#define NCH 64         // n_channels
#define TRAW 16384     // raw samples
#define TPAD 16448     // TRAW + 64 (left reflect pad)
#define TP 4112        // TPAD / 4
#define TE 4104        // TP - 8  (after encoder MA, kernel size 9)
#define TD 4096        // TE - 8  (after decoder MA) == TRAW/4

// Workspace layout (float offsets)
#define OFF_SPAD   0u          // fp32 [32][16448]
#define OFF_AMEAN  526336u     // fp32 [32][4112]; ameant [32][4096] aliases after consumption
#define OFF_AHI    657920u     // ushort [4112][1024] (bf16 hi of acov)
#define OFF_ALO    2763264u    // ushort [4112][1024] (bf16 lo)
#define OFF_ACOVT  657920u     // fp32 [4096][1024] — aliases AHI+ALO after encoder macov consumed them
#define OFF_XMEAN  4868608u    // fp32 [32][4104]
#define OFF_XHI    4999936u    // ushort [4104][1024] (xcov hi)
#define OFF_XLO    7101184u    // ushort [4104][1024] (xcov lo)
#define OFF_FBEH   9202432u    // ushort [9][1024] encoder filter hi (k=8 = identity)
#define OFF_FBEL   9207040u
#define OFF_FBDH   9211648u
#define OFF_FBDL   9216256u    // end 9220864 floats = 36.9 MB

typedef __attribute__((ext_vector_type(8))) short bf16x8;
typedef __attribute__((ext_vector_type(16))) float f32x16;
#define MFMA(a, b, c) __builtin_amdgcn_mfma_f32_32x32x16_bf16(a, b, c, 0, 0, 0)

union FragU { int4 i; bf16x8 b; };
__device__ inline bf16x8 ld_frag16(const ushort* p) {
    FragU u; u.i = *(const int4*)p; return u.b;
}
__device__ inline bf16x8 frag_from2(const ushort* p1, const ushort* p2) {
    FragU u; uint2 a = *(const uint2*)p1, b = *(const uint2*)p2;
    u.i = make_int4(a.x, a.y, b.x, b.y); return u.b;
}
__device__ inline bf16x8 frag_pack(unsigned d0, unsigned d1, unsigned d2, unsigned d3) {
    FragU u; u.i = make_int4(d0, d1, d2, d3); return u.b;
}
// truncation split: x = hi + lo with hi = trunc16(x), lo = trunc16(x - hi); err ~2^-16 rel
__device__ inline void split_store(float v, ushort* ph, ushort* pl) {
    unsigned b = __float_as_uint(v);
    *ph = (ushort)(b >> 16);
    float lo = v - __uint_as_float(b & 0xffff0000u);
    *pl = (ushort)(__float_as_uint(lo) >> 16);
}

// ---------------------------------------------------------------------------
// 0) filter prep: Fb[k][c][C] = filtr (k<8: maw, k=8: identity), bf16 hi/lo
__global__ void fprep_kernel(const float* __restrict__ maw,
                             ushort* __restrict__ Fh, ushort* __restrict__ Fl) {
    int idx = blockIdx.x * 256 + threadIdx.x;   // 0..9215
    if (idx >= 9216) return;
    int k = idx >> 10, r = idx & 1023, c = r >> 5, C = r & 31;
    float v = (k < 8) ? maw[(c * NF + C) * 8 + k] : (c == C ? 1.f : 0.f);
    split_store(v, Fh + idx, Fl + idx);
}

// ---------------------------------------------------------------------------
// 1) s_pad[f,t] = sum_c W_enc[f,c] * y_pad[c,t],  y_pad[c,t] = y[c, |t-64|]
__global__ void senc_kernel(const float* __restrict__ y,
                            const float* __restrict__ Wenc,
                            float* __restrict__ spad) {
    int t = blockIdx.x * 256 + threadIdx.x;
    int f = blockIdx.y;
    if (t >= TPAD) return;
    int tt = (t >= 64) ? (t - 64) : (64 - t);   // reflect pad
    float acc = 0.f;
#pragma unroll
    for (int c = 0; c < NCH; ++c)
        acc = fmaf(Wenc[f * NCH + c], y[c * TRAW + tt], acc);
    spad[f * TPAD + t] = acc;
}

// ---------------------------------------------------------------------------
// 2) per-t4 stats: a_mean fp32; a_cov emitted as bf16 hi/lo split
__global__ __launch_bounds__(256) void stats_kernel(const float* __restrict__ spad,
                                                    float* __restrict__ amean,
                                                    ushort* __restrict__ Ah,
                                                    ushort* __restrict__ Al) {
    __shared__ float sab[32][33];
    __shared__ float mu[32][9];
    int tid = threadIdx.x;
    int t0 = blockIdx.x * 8;        // 514 blocks * 8 = 4112
#pragma unroll
    for (int i = 0; i < 4; ++i) {
        int idx = tid + 256 * i;    // 0..1023
        int f = idx >> 5, j = idx & 31;
        sab[f][j] = fabsf(spad[f * TPAD + t0 * 4 + j]);
    }
    __syncthreads();
    {
        int f = tid >> 3, tt = tid & 7;
        float m = 0.25f * (sab[f][tt * 4] + sab[f][tt * 4 + 1] +
                           sab[f][tt * 4 + 2] + sab[f][tt * 4 + 3]);
        mu[f][tt] = m;
        amean[f * TP + t0 + tt] = m;
    }
    __syncthreads();
    const float inv3 = 1.f / 3.f;
#pragma unroll
    for (int e = 0; e < 32; ++e) {
        int flat = e * 256 + tid;   // 0..8191
        int tt = flat >> 10, r = flat & 1023;
        int c = r >> 5, s = r & 31;
        float mc = mu[c][tt], ms = mu[s][tt];
        float acc = 0.f;
#pragma unroll
        for (int d = 0; d < 4; ++d)
            acc += (sab[c][tt * 4 + d] - mc) * (sab[s][tt * 4 + d] - ms);
        size_t oidx = (size_t)(t0 + tt) * 1024 + r;
        split_store(acc * inv3, Ah + oidx, Al + oidx);
    }
}

// ---------------------------------------------------------------------------
// 3/5) mean MA: out[c,t] = b[c] + in[c,t+8] + sum_{k<8,C} w[c,C,k]*in[C,t+k]
__global__ void mamean_kernel(const float* __restrict__ in, int instride,
                              const float* __restrict__ w,
                              const float* __restrict__ b,
                              float* __restrict__ outp, int Tout) {
    int t = blockIdx.x * 256 + threadIdx.x;
    int c = blockIdx.y;
    if (t >= Tout) return;
    float acc = b[c] + in[c * instride + t + 8];
    for (int C = 0; C < NF; ++C) {
#pragma unroll
        for (int k = 0; k < 8; ++k)
            acc = fmaf(w[(c * NF + C) * 8 + k], in[C * instride + t + k], acc);
    }
    outp[c * Tout + t] = acc;
}

// ---------------------------------------------------------------------------
// 4/6) cov MA v7 (MFMA): Out_t = sum_{k=0..8} F_k A_{t+k} F_k^T  (F_8 = I)
//  One wave per t; inputs bf16 hi/lo split; 3-term split products (drop lo*lo).
//  step1: H = A * F^T   (X = A-operand frag, Y = F row-major frag)
//  step2: Out += F * H with K-slot permutation chosen so Y2 = lane-local
//         pairwise-packed hacc registers (no cross-lane exchange):
//         mfma#m sums C in {m*16+{0-3,8-11}} (lanes<32) ∪ {m*16+{4-7,12-15}} (lanes>=32)
//  A-operand: lane l -> row l&31, k = (l>>5)*8+i ; B-operand mirrored.
//  D: col = l&31, row m = (r&3)+8*(r>>2)+4*(l>>5)   [guide-verified]
template<int SPLIT_OUT>
__global__ __launch_bounds__(256) void macov_mfma(
    const ushort* __restrict__ Ah, const ushort* __restrict__ Al,
    const ushort* __restrict__ Fh, const ushort* __restrict__ Fl,
    const float* __restrict__ scale_ptr,
    float* __restrict__ OutF, ushort* __restrict__ OHi, ushort* __restrict__ OLo)
{
    int tid = threadIdx.x;
    int w = tid >> 6, l = tid & 63;
    int t = blockIdx.x * 4 + w;
    int ln = l & 31, hiL = l >> 5;
    f32x16 acc;
#pragma unroll
    for (int r = 0; r < 16; ++r) acc[r] = 0.f;
    int roff = ln * 32 + hiL * 8;      // 16B-frag element offset within a 32x32 tile

#pragma unroll 1
    for (int k = 0; k < 9; ++k) {
        const ushort* Abh = Ah + (size_t)(t + k) * 1024;
        const ushort* Abl = Al + (size_t)(t + k) * 1024;
        const ushort* Fkh = Fh + k * 1024;
        const ushort* Fkl = Fl + k * 1024;
        bf16x8 aH0 = ld_frag16(Abh + roff);
        bf16x8 aH1 = ld_frag16(Abh + roff + 16);
        bf16x8 aL0 = ld_frag16(Abl + roff);
        bf16x8 aL1 = ld_frag16(Abl + roff + 16);
        bf16x8 fH0 = ld_frag16(Fkh + roff);
        bf16x8 fH1 = ld_frag16(Fkh + roff + 16);
        bf16x8 fL0 = ld_frag16(Fkl + roff);
        bf16x8 fL1 = ld_frag16(Fkl + roff + 16);
        // step1: H = A*F^T (3-term split, kk-halves 0/1)
        f32x16 h;
#pragma unroll
        for (int r = 0; r < 16; ++r) h[r] = 0.f;
        h = MFMA(aH0, fH0, h); h = MFMA(aH1, fH1, h);
        h = MFMA(aH0, fL0, h); h = MFMA(aH1, fL1, h);
        h = MFMA(aL0, fH0, h); h = MFMA(aL1, fH1, h);
        // pack H -> bf16 hi/lo Y2 frags (pairwise, lane-local)
        unsigned dh0, dh1, dh2, dh3, dh4, dh5, dh6, dh7;
        unsigned dl0, dl1, dl2, dl3, dl4, dl5, dl6, dl7;
#define PACKJ(J, DH, DL) { \
        unsigned b0 = __float_as_uint(h[2*J]); \
        unsigned b1 = __float_as_uint(h[2*J+1]); \
        DH = (b0 >> 16) | (b1 & 0xffff0000u); \
        float p0 = h[2*J]   - __uint_as_float(b0 & 0xffff0000u); \
        float p1 = h[2*J+1] - __uint_as_float(b1 & 0xffff0000u); \
        DL = (__float_as_uint(p0) >> 16) | (__float_as_uint(p1) & 0xffff0000u); }
        PACKJ(0, dh0, dl0) PACKJ(1, dh1, dl1) PACKJ(2, dh2, dl2) PACKJ(3, dh3, dl3)
        PACKJ(4, dh4, dl4) PACKJ(5, dh5, dl5) PACKJ(6, dh6, dl6) PACKJ(7, dh7, dl7)
#undef PACKJ
        bf16x8 yH0 = frag_pack(dh0, dh1, dh2, dh3);
        bf16x8 yH1 = frag_pack(dh4, dh5, dh6, dh7);
        bf16x8 yL0 = frag_pack(dl0, dl1, dl2, dl3);
        bf16x8 yL1 = frag_pack(dl4, dl5, dl6, dl7);
        // step2 X frags: F with permuted cols: chunks (m*16 + hiL*4, m*16+8+hiL*4)
        const ushort* Frh = Fkh + ln * 32;
        const ushort* Frl = Fkl + ln * 32;
        bf16x8 xH0 = frag_from2(Frh + hiL * 4,      Frh + 8 + hiL * 4);
        bf16x8 xH1 = frag_from2(Frh + 16 + hiL * 4, Frh + 24 + hiL * 4);
        bf16x8 xL0 = frag_from2(Frl + hiL * 4,      Frl + 8 + hiL * 4);
        bf16x8 xL1 = frag_from2(Frl + 16 + hiL * 4, Frl + 24 + hiL * 4);
        acc = MFMA(xH0, yH0, acc); acc = MFMA(xH1, yH1, acc);
        acc = MFMA(xH0, yL0, acc); acc = MFMA(xH1, yL1, acc);
        acc = MFMA(xL0, yH0, acc); acc = MFMA(xL1, yH1, acc);
    }
    float sc = scale_ptr ? *scale_ptr : 1.f;
#pragma unroll
    for (int r = 0; r < 16; ++r) {
        int m = (r & 3) + 8 * (r >> 2) + 4 * hiL;
        size_t idx = (size_t)t * 1024 + m * 32 + ln;
        float v = acc[r] * sc;
        if (SPLIT_OUT) split_store(v, OHi + idx, OLo + idx);
        else           OutF[idx] = v;
    }
}

// ---------------------------------------------------------------------------
// 7) y_mean rows 0..63
__global__ void ymean_kernel(const float* __restrict__ spad,
                             const float* __restrict__ ameant,
                             const float* __restrict__ Wdec,
                             float* __restrict__ out) {
    int t = blockIdx.x * 256 + threadIdx.x;   // < 16384
    int o = blockIdx.y;
    int t4 = t >> 2;
    float acc = 0.f;
#pragma unroll
    for (int f = 0; f < NF; ++f) {
        float sp = spad[f * TPAD + 64 + t];
        float sgn = (sp > 0.f) ? 1.f : (sp < 0.f ? -1.f : 0.f);
        acc = fmaf(Wdec[o * NF + f], ameant[f * TD + t4] * sgn, acc);
    }
    out[o * TRAW + t] = acc;
}

// ---------------------------------------------------------------------------
// 8) y_cov rows 64..4159. Full 64B-line coalesced stores. (unchanged)
#define B4S 2056
__global__ __launch_bounds__(256) void ycov_kernel(const float* __restrict__ Acovt,
                                                   const float* __restrict__ Wdec,
                                                   float* __restrict__ out) {
    __shared__ __align__(16) float W2[64 * 32];
    __shared__ __align__(16) float B4[4 * B4S];
    int tid = threadIdx.x;
    int T0 = blockIdx.x * 4;        // gridDim.x == 1024
#pragma unroll
    for (int i = 0; i < 8; ++i) {
        int idx = tid + 256 * i;
        W2[idx] = Wdec[idx];
    }
    __syncthreads();
    {
        int t4l = tid >> 6, I = tid & 31, half = (tid >> 5) & 1;
        const float* Arow = Acovt + (size_t)(T0 + t4l) * 1024;
        float areg[32];
#pragma unroll
        for (int i = 0; i < 32; ++i) areg[i] = Arow[i * 32 + I];
        float* Bb = B4 + t4l * B4S + I;
#pragma unroll 4
        for (int oj = 0; oj < 32; ++oj) {
            int o = half * 32 + oj;
            const float4* Wr = (const float4*)(W2 + o * 32);
            float a0 = 0.f, a1 = 0.f, a2 = 0.f, a3 = 0.f;
#pragma unroll
            for (int j = 0; j < 8; j += 4) {
                float4 w0 = Wr[j], w1 = Wr[j + 1], w2 = Wr[j + 2], w3 = Wr[j + 3];
                a0 = fmaf(w0.x, areg[4 * j + 0], a0);  a0 = fmaf(w0.y, areg[4 * j + 1], a0);
                a1 = fmaf(w0.z, areg[4 * j + 2], a1);  a1 = fmaf(w0.w, areg[4 * j + 3], a1);
                a0 = fmaf(w1.x, areg[4 * j + 4], a0);  a0 = fmaf(w1.y, areg[4 * j + 5], a0);
                a1 = fmaf(w1.z, areg[4 * j + 6], a1);  a1 = fmaf(w1.w, areg[4 * j + 7], a1);
                a2 = fmaf(w2.x, areg[4 * j + 8], a2);  a2 = fmaf(w2.y, areg[4 * j + 9], a2);
                a3 = fmaf(w2.z, areg[4 * j + 10], a3); a3 = fmaf(w2.w, areg[4 * j + 11], a3);
                a2 = fmaf(w3.x, areg[4 * j + 12], a2); a2 = fmaf(w3.y, areg[4 * j + 13], a2);
                a3 = fmaf(w3.z, areg[4 * j + 14], a3); a3 = fmaf(w3.w, areg[4 * j + 15], a3);
            }
            Bb[o * 32] = (a0 + a1) + (a2 + a3);
        }
    }
    __syncthreads();
    {
        int O = tid >> 2, t4l = tid & 3;
        float4 wv[8];
#pragma unroll
        for (int j = 0; j < 8; ++j) wv[j] = ((const float4*)(Wdec + O * 32))[j];
        float4* out4 = (float4*)out;
        const float* Bbase = B4 + t4l * B4S;
#pragma unroll 2
        for (int o = 0; o < 64; ++o) {
            const float4* Br = (const float4*)(Bbase + o * 32);
            float a0 = 0.f, a1 = 0.f, a2 = 0.f, a3 = 0.f;
#pragma unroll
            for (int j = 0; j < 8; j += 4) {
                float4 b0 = Br[j], b1 = Br[j + 1], b2 = Br[j + 2], b3 = Br[j + 3];
                a0 = fmaf(b0.x, wv[j].x, a0);      a0 = fmaf(b0.y, wv[j].y, a0);
                a1 = fmaf(b0.z, wv[j].z, a1);      a1 = fmaf(b0.w, wv[j].w, a1);
                a0 = fmaf(b1.x, wv[j + 1].x, a0);  a0 = fmaf(b1.y, wv[j + 1].y, a0);
                a1 = fmaf(b1.z, wv[j + 1].z, a1);  a1 = fmaf(b1.w, wv[j + 1].w, a1);
                a2 = fmaf(b2.x, wv[j + 2].x, a2);  a2 = fmaf(b2.y, wv[j + 2].y, a2);
                a3 = fmaf(b2.z, wv[j + 2].z, a3);  a3 = fmaf(b2.w, wv[j + 2].w, a3);
                a2 = fmaf(b3.x, wv[j + 3].x, a2);  a2 = fmaf(b3.y, wv[j + 3].y, a2);
                a3 = fmaf(b3.z, wv[j + 3].z, a3);  a3 = fmaf(b3.w, wv[j + 3].w, a3);
            }
            float acc = (a0 + a1) + (a2 + a3);
            size_t r = 64 + o * 64 + O;
            out4[r * (TRAW / 4) + T0 + t4l] = make_float4(acc, acc, acc, acc);
        }
    }
}

// ---------------------------------------------------------------------------
extern "C" void kernel_launch(void* const* d_in, const int* in_sizes, int n_in,
                              void* d_out, int out_size, void* d_ws, size_t ws_size,
                              hipStream_t stream) {
    const float* y      = (const float*)d_in[0];
    const float* Wenc   = (const float*)d_in[1];
    const float* Wdec   = (const float*)d_in[2];
    const float* mawE   = (const float*)d_in[3];
    const float* mabE   = (const float*)d_in[4];
    const float* mawD   = (const float*)d_in[5];
    const float* mabD   = (const float*)d_in[6];
    const float* covsc  = (const float*)d_in[7];
    float* out = (float*)d_out;
    float* ws  = (float*)d_ws;

    float*  spad   = ws + OFF_SPAD;
    float*  amean  = ws + OFF_AMEAN;
    float*  xmean  = ws + OFF_XMEAN;
    float*  ameant = ws + OFF_AMEAN;               // alias (amean consumed)
    float*  acovt  = ws + OFF_ACOVT;               // alias (Ahi/Alo consumed)
    ushort* Ahi    = (ushort*)(ws + OFF_AHI);
    ushort* Alo    = (ushort*)(ws + OFF_ALO);
    ushort* Xhi    = (ushort*)(ws + OFF_XHI);
    ushort* Xlo    = (ushort*)(ws + OFF_XLO);
    ushort* FbEh   = (ushort*)(ws + OFF_FBEH);
    ushort* FbEl   = (ushort*)(ws + OFF_FBEL);
    ushort* FbDh   = (ushort*)(ws + OFF_FBDH);
    ushort* FbDl   = (ushort*)(ws + OFF_FBDL);

    // 0) filter prep (bf16 hi/lo, 9th tap = identity)
    fprep_kernel<<<dim3(36), 256, 0, stream>>>(mawE, FbEh, FbEl);
    fprep_kernel<<<dim3(36), 256, 0, stream>>>(mawD, FbDh, FbDl);
    // 1) spatial encode + pad
    senc_kernel<<<dim3((TPAD + 255) / 256, NF), 256, 0, stream>>>(y, Wenc, spad);
    // 2) downsample stats (cov emitted bf16-split)
    stats_kernel<<<dim3(TP / 8), 256, 0, stream>>>(spad, amean, Ahi, Alo);
    // 3) encoder mean MA
    mamean_kernel<<<dim3((TE + 255) / 256, NF), 256, 0, stream>>>(amean, TP, mawE, mabE, xmean, TE);
    // 4) encoder cov MA (MFMA), output bf16-split, scaled by cov_scaler
    macov_mfma<1><<<dim3(TE / 4), 256, 0, stream>>>(Ahi, Alo, FbEh, FbEl, covsc,
                                                    nullptr, Xhi, Xlo);
    // 5) decoder mean MA
    mamean_kernel<<<dim3((TD + 255) / 256, NF), 256, 0, stream>>>(xmean, TE, mawD, mabD, ameant, TD);
    // 6) decoder cov MA (MFMA), output fp32
    macov_mfma<0><<<dim3(TD / 4), 256, 0, stream>>>(Xhi, Xlo, FbDh, FbDl, nullptr,
                                                    acovt, nullptr, nullptr);
    // 7) y_mean
    ymean_kernel<<<dim3(TRAW / 256, NCH), 256, 0, stream>>>(spad, ameant, Wdec, out);
    // 8) y_cov — 4 t4 per block
    ycov_kernel<<<dim3(TD / 4), 256, 0, stream>>>(acovt, Wdec, out);
}